// Round 4
// baseline (580.852 us; speedup 1.0000x reference)
//
#include <hip/hip_runtime.h>

#define NN 384
#define RR 8
#define NR (NN * RR)   // 3072
#define BB 64          // (j,k) pairs per block
#define PSTR 72        // padded LDS row stride (bf16 elems); 72*2B=144B

typedef short short8 __attribute__((ext_vector_type(8)));   // 8 bf16

static __device__ inline unsigned short f2bf(float f) {
    unsigned u = __builtin_bit_cast(unsigned, f);
    u += 0x7FFF + ((u >> 16) & 1);          // RNE round to bf16
    return (unsigned short)(u >> 16);
}
static __device__ inline float bf2f(short s) {
    unsigned u = ((unsigned)(unsigned short)s) << 16;
    return __builtin_bit_cast(float, u);
}

// out[b,i] = sum_{a,b2,c} A[a,i,b2] * Bf[b2,j_b,c] * C[c,k_b,a]
// G[b2,a] = sum_c Bf[b2,j,c]*C[c,k,a];  out[b,i] = sum_p A2[i,p]*Gv[p], p=a*8+b2.
// DIAGNOSTIC ROUND: identical staging + G as round 3, but pure-VALU dot epilogue
// (no MFMA) to bisect {staging,G,indexing} vs {MFMA input layout}.
__global__ __launch_bounds__(256, 2)
void dtn_valu(const float* __restrict__ A, const float* __restrict__ Bf,
              const float* __restrict__ C, const int* __restrict__ x,
              float* __restrict__ out)
{
    __shared__ __align__(16) unsigned short A2s[NN * PSTR];   // [i][p], p=a*8+b2
    __shared__ __align__(16) unsigned short Gs[BB * PSTR];    // [b_local][p]

    const int t = threadIdx.x;
    const long b0 = (long)blockIdx.x * BB;

    // ---- Stage A2s[i][a*8+b2] = bf16(A[a,i,b2]) ---- (identical to round 3)
    #pragma unroll
    for (int c = 0; c < 12; ++c) {
        const int idx = t + c * 256;      // 0..3071
        const int i = idx >> 3;
        const int a = idx & 7;
        const float4* src = reinterpret_cast<const float4*>(A + (size_t)a * NR + (size_t)i * RR);
        const float4 f0 = src[0];
        const float4 f1 = src[1];
        short8 h;
        h[0] = (short)f2bf(f0.x); h[1] = (short)f2bf(f0.y); h[2] = (short)f2bf(f0.z); h[3] = (short)f2bf(f0.w);
        h[4] = (short)f2bf(f1.x); h[5] = (short)f2bf(f1.y); h[6] = (short)f2bf(f1.z); h[7] = (short)f2bf(f1.w);
        *reinterpret_cast<short8*>(&A2s[i * PSTR + a * 8]) = h;
    }

    // ---- G for 64 pairs ---- (identical to round 3)
    {
        const int bl = t >> 2;
        const int a0 = (t & 3) * 2;
        const int j = x[2 * (b0 + bl)];
        const int k = x[2 * (b0 + bl) + 1];
        const float* Bj = Bf + (size_t)j * RR;       // Bf[b2,j,c] at Bj[b2*NR + c]
        const float* Ck = C + (size_t)k * RR + a0;   // C[c,k,a0+d] at Ck[c*NR + d]
        float2 ck[8];
        #pragma unroll
        for (int c = 0; c < 8; ++c)
            ck[c] = *reinterpret_cast<const float2*>(Ck + (size_t)c * NR);
        short8 h0, h1;
        #pragma unroll
        for (int b2 = 0; b2 < 8; ++b2) {
            const float4* br = reinterpret_cast<const float4*>(Bj + (size_t)b2 * NR);
            const float4 r0 = br[0];
            const float4 r1 = br[1];
            const float s0 = r0.x * ck[0].x + r0.y * ck[1].x + r0.z * ck[2].x + r0.w * ck[3].x
                           + r1.x * ck[4].x + r1.y * ck[5].x + r1.z * ck[6].x + r1.w * ck[7].x;
            const float s1 = r0.x * ck[0].y + r0.y * ck[1].y + r0.z * ck[2].y + r0.w * ck[3].y
                           + r1.x * ck[4].y + r1.y * ck[5].y + r1.z * ck[6].y + r1.w * ck[7].y;
            h0[b2] = (short)f2bf(s0);
            h1[b2] = (short)f2bf(s1);
        }
        *reinterpret_cast<short8*>(&Gs[bl * PSTR + a0 * 8]) = h0;       // p = a0*8 + b2
        *reinterpret_cast<short8*>(&Gs[bl * PSTR + a0 * 8 + 8]) = h1;   // p = (a0+1)*8 + b2
    }

    __syncthreads();

    // ---- VALU epilogue: thread t -> pair bl = t>>2, quarter q = t&3.
    // Each thread computes 96 i-values as 24 groups of 4 consecutive i (float4 store).
    {
        const int bl = t >> 2;
        const int q = t & 3;

        // Convert this pair's G row to 64 f32 (all indices compile-time -> registers)
        float Gf[64];
        #pragma unroll
        for (int p8 = 0; p8 < 8; ++p8) {
            short8 g = *reinterpret_cast<const short8*>(&Gs[bl * PSTR + p8 * 8]);
            #pragma unroll
            for (int jj = 0; jj < 8; ++jj)
                Gf[p8 * 8 + jj] = bf2f(g[jj]);
        }

        float* outrow = out + (size_t)(b0 + bl) * NN;
        for (int v = 0; v < 24; ++v) {
            const int i0 = (q + 4 * v) * 4;      // 16B-aligned group of 4 i's
            float sums[4];
            #pragma unroll
            for (int w = 0; w < 4; ++w) {
                const int i = i0 + w;
                float sum = 0.f;
                #pragma unroll
                for (int p8 = 0; p8 < 8; ++p8) {
                    short8 av = *reinterpret_cast<const short8*>(&A2s[i * PSTR + p8 * 8]);
                    #pragma unroll
                    for (int jj = 0; jj < 8; ++jj)
                        sum += bf2f(av[jj]) * Gf[p8 * 8 + jj];
                }
                sums[w] = sum;
            }
            float4 res;
            res.x = sums[0]; res.y = sums[1]; res.z = sums[2]; res.w = sums[3];
            *reinterpret_cast<float4*>(outrow + i0) = res;
        }
    }
}

extern "C" void kernel_launch(void* const* d_in, const int* in_sizes, int n_in,
                              void* d_out, int out_size, void* d_ws, size_t ws_size,
                              hipStream_t stream) {
    const float* A  = (const float*)d_in[0];
    const float* Bf = (const float*)d_in[1];
    const float* C  = (const float*)d_in[2];
    const int*   x  = (const int*)d_in[3];
    float* out = (float*)d_out;
    const int B = in_sizes[3] / 2;           // 524288
    dtn_valu<<<B / BB, 256, 0, stream>>>(A, Bf, C, x, out);
}

// Round 7
// 301.510 us; speedup vs baseline: 1.9265x; 1.9265x over previous
//
#include <hip/hip_runtime.h>

#define NN 384
#define RR 8
#define NR (NN * RR)   // 3072
#define BB 64          // (j,k) pairs per block

typedef _Float16 half2v __attribute__((ext_vector_type(2)));
typedef _Float16 half8v __attribute__((ext_vector_type(8)));

struct h2x4 { half2v v[4]; };
static __device__ inline h2x4 split4(half8v h) { return __builtin_bit_cast(h2x4, h); }

// out[b,i] = sum_{a,b2,c} A[a,i,b2]*Bf[b2,j_b,c]*C[c,k_b,a]
// G[b2,a] = sum_c Bf[b2,j,c]*C[c,k,a];  out[b,i] = sum_p A2[i,p]*G[p], p=a*8+b2.
// Proven-correct VALU path (round 4), optimized: f16 LDS + v_dot2_f32_f16,
// 8x12 register tile per thread, bank-spread chunk-major A2 layout.
__global__ __launch_bounds__(256, 2)
void dtn_dot2(const float* __restrict__ A, const float* __restrict__ Bf,
              const float* __restrict__ C, const int* __restrict__ x,
              float* __restrict__ out)
{
    // A2c[c][i]: 16B chunk = f16 of A2[i][8c..8c+7]  (chunk-major: word-bank = 4i%32)
    __shared__ __align__(16) _Float16 A2c[8 * NN * 8];   // 49152 B
    __shared__ __align__(16) _Float16 Gh[BB * 64];       // 8192 B

    const int t = threadIdx.x;
    const long b0 = (long)blockIdx.x * BB;

    // ---- Stage A2c[(a*NN+i)*8 + e] = f16(A[a*NR + i*8 + e]); 3072 8-float chunks.
    #pragma unroll
    for (int it = 0; it < 12; ++it) {
        const int idx = t + it * 256;     // 0..3071
        const int i = idx >> 3;
        const int a = idx & 7;
        const float4* src = reinterpret_cast<const float4*>(A + (size_t)a * NR + (size_t)i * RR);
        const float4 f0 = src[0];
        const float4 f1 = src[1];
        half8v h;
        h[0] = (_Float16)f0.x; h[1] = (_Float16)f0.y; h[2] = (_Float16)f0.z; h[3] = (_Float16)f0.w;
        h[4] = (_Float16)f1.x; h[5] = (_Float16)f1.y; h[6] = (_Float16)f1.z; h[7] = (_Float16)f1.w;
        *reinterpret_cast<half8v*>(&A2c[(size_t)(a * NN + i) * 8]) = h;
    }

    // ---- G for this block's 64 pairs (math identical to passing round 4; f16 out).
    {
        const int bl = t >> 2;
        const int a0 = (t & 3) * 2;
        const int j = x[2 * (b0 + bl)];
        const int k = x[2 * (b0 + bl) + 1];
        const float* Bj = Bf + (size_t)j * RR;       // Bf[b2,j,c] at Bj[b2*NR + c]
        const float* Ck = C + (size_t)k * RR + a0;   // C[c,k,a0+d] at Ck[c*NR + d]
        float2 ck[8];
        #pragma unroll
        for (int c = 0; c < 8; ++c)
            ck[c] = *reinterpret_cast<const float2*>(Ck + (size_t)c * NR);
        half8v h0, h1;
        #pragma unroll
        for (int b2 = 0; b2 < 8; ++b2) {
            const float4* br = reinterpret_cast<const float4*>(Bj + (size_t)b2 * NR);
            const float4 r0 = br[0];
            const float4 r1 = br[1];
            const float s0 = r0.x * ck[0].x + r0.y * ck[1].x + r0.z * ck[2].x + r0.w * ck[3].x
                           + r1.x * ck[4].x + r1.y * ck[5].x + r1.z * ck[6].x + r1.w * ck[7].x;
            const float s1 = r0.x * ck[0].y + r0.y * ck[1].y + r0.z * ck[2].y + r0.w * ck[3].y
                           + r1.x * ck[4].y + r1.y * ck[5].y + r1.z * ck[6].y + r1.w * ck[7].y;
            h0[b2] = (_Float16)s0;
            h1[b2] = (_Float16)s1;
        }
        *reinterpret_cast<half8v*>(&Gh[bl * 64 + a0 * 8]) = h0;       // p = a0*8 + b2
        *reinterpret_cast<half8v*>(&Gh[bl * 64 + a0 * 8 + 8]) = h1;   // p = (a0+1)*8 + b2
    }

    __syncthreads();

    // ---- Epilogue: thread (pg = t>>5, ig = t&31) computes 8 pairs x 12 i's,
    // i = ig + 32*ii (strided so the wave's 32 ig-lanes span all LDS bank groups).
    const int pg = t >> 5;
    const int ig = t & 31;

    float acc[8][12];
    #pragma unroll
    for (int pp = 0; pp < 8; ++pp)
        #pragma unroll
        for (int ii = 0; ii < 12; ++ii)
            acc[pp][ii] = 0.f;

    #pragma unroll 1
    for (int c = 0; c < 8; ++c) {
        h2x4 g[8];
        h2x4 av[12];
        #pragma unroll
        for (int pp = 0; pp < 8; ++pp)
            g[pp] = split4(*reinterpret_cast<const half8v*>(&Gh[(pg * 8 + pp) * 64 + c * 8]));
        #pragma unroll
        for (int ii = 0; ii < 12; ++ii)
            av[ii] = split4(*reinterpret_cast<const half8v*>(&A2c[(size_t)(c * NN + (ig + 32 * ii)) * 8]));
        #pragma unroll
        for (int pp = 0; pp < 8; ++pp) {
            #pragma unroll
            for (int ii = 0; ii < 12; ++ii) {
                float s = acc[pp][ii];
                s = __builtin_amdgcn_fdot2(g[pp].v[0], av[ii].v[0], s, false);
                s = __builtin_amdgcn_fdot2(g[pp].v[1], av[ii].v[1], s, false);
                s = __builtin_amdgcn_fdot2(g[pp].v[2], av[ii].v[2], s, false);
                s = __builtin_amdgcn_fdot2(g[pp].v[3], av[ii].v[3], s, false);
                acc[pp][ii] = s;
            }
        }
    }

    // ---- Store: per (pp,ii) lanes ig=0..31 write 128B contiguous — coalesced.
    #pragma unroll
    for (int pp = 0; pp < 8; ++pp) {
        float* orow = out + (size_t)(b0 + pg * 8 + pp) * NN + ig;
        #pragma unroll
        for (int ii = 0; ii < 12; ++ii)
            orow[ii * 32] = acc[pp][ii];
    }
}

extern "C" void kernel_launch(void* const* d_in, const int* in_sizes, int n_in,
                              void* d_out, int out_size, void* d_ws, size_t ws_size,
                              hipStream_t stream) {
    const float* A  = (const float*)d_in[0];
    const float* Bf = (const float*)d_in[1];
    const float* C  = (const float*)d_in[2];
    const int*   x  = (const int*)d_in[3];
    float* out = (float*)d_out;
    const int B = in_sizes[3] / 2;           // 524288
    dtn_dot2<<<B / BB, 256, 0, stream>>>(A, Bf, C, x, out);
}

// Round 8
// 285.042 us; speedup vs baseline: 2.0378x; 1.0578x over previous
//
#include <hip/hip_runtime.h>

#define NN 384
#define RR 8
#define NR (NN * RR)   // 3072
#define BB 64          // (j,k) pairs per block

typedef _Float16 half2v __attribute__((ext_vector_type(2)));
typedef _Float16 half8v __attribute__((ext_vector_type(8)));

struct h2x4 { half2v v[4]; };
static __device__ inline h2x4 split4(half8v h) { return __builtin_bit_cast(h2x4, h); }

// out[b,i] = sum_{a,b2,c} A[a,i,b2]*Bf[b2,j_b,c]*C[c,k_b,a]
// G[b2,a] = sum_c Bf[b2,j,c]*C[c,k,a];  out[b,i] = sum_p A2[i,p]*G[p], p=a*8+b2.
// Occupancy-tuned dot2 path: 512 thr/block, 8 pairs x 6 i per thread (~90 VGPR
// -> 4 waves/SIMD), wave-contiguous LDS reads, broadcast G reads.
__global__ __launch_bounds__(512, 4)
void dtn_dot2b(const float* __restrict__ A, const float* __restrict__ Bf,
               const float* __restrict__ C, const int* __restrict__ x,
               float* __restrict__ out)
{
    // A2c[c][i]: 16B chunk = f16 of A2[i][8c..8c+7]
    __shared__ __align__(16) _Float16 A2c[8 * NN * 8];   // 49152 B
    __shared__ __align__(16) _Float16 Gh[BB * 64];       // 8192 B

    const int t = threadIdx.x;
    const long b0 = (long)blockIdx.x * BB;

    // ---- Stage A2c[(a*NN+i)*8 + e] = f16(A[a*NR + i*8 + e]); 3072 chunks, 6 iters.
    #pragma unroll
    for (int it = 0; it < 6; ++it) {
        const int idx = t + it * 512;     // 0..3071
        const int i = idx >> 3;
        const int a = idx & 7;
        const float4* src = reinterpret_cast<const float4*>(A + (size_t)a * NR + (size_t)i * RR);
        const float4 f0 = src[0];
        const float4 f1 = src[1];
        half8v h;
        h[0] = (_Float16)f0.x; h[1] = (_Float16)f0.y; h[2] = (_Float16)f0.z; h[3] = (_Float16)f0.w;
        h[4] = (_Float16)f1.x; h[5] = (_Float16)f1.y; h[6] = (_Float16)f1.z; h[7] = (_Float16)f1.w;
        *reinterpret_cast<half8v*>(&A2c[(size_t)(a * NN + i) * 8]) = h;
    }

    // ---- G: thread -> (pair bl = t>>3, column a = t&7); computes G[b2][a], b2=0..7.
    // Math identical to the proven round-4/7 path, just remapped to 512 threads.
    {
        const int bl = t >> 3;
        const int a  = t & 7;
        const int j = x[2 * (b0 + bl)];
        const int k = x[2 * (b0 + bl) + 1];
        const float* Bj = Bf + (size_t)j * RR;           // Bf[b2,j,c] at Bj[b2*NR + c]
        const float* Ck = C + (size_t)k * RR + a;        // C[c,k,a]   at Ck[c*NR]
        float ck[8];
        #pragma unroll
        for (int c = 0; c < 8; ++c)
            ck[c] = Ck[(size_t)c * NR];
        half8v h;
        #pragma unroll
        for (int b2 = 0; b2 < 8; ++b2) {
            const float4* br = reinterpret_cast<const float4*>(Bj + (size_t)b2 * NR);
            const float4 r0 = br[0];
            const float4 r1 = br[1];
            const float s = r0.x * ck[0] + r0.y * ck[1] + r0.z * ck[2] + r0.w * ck[3]
                          + r1.x * ck[4] + r1.y * ck[5] + r1.z * ck[6] + r1.w * ck[7];
            h[b2] = (_Float16)s;
        }
        *reinterpret_cast<half8v*>(&Gh[bl * 64 + a * 8]) = h;   // p = a*8 + b2
    }

    __syncthreads();

    // ---- Epilogue: lane = t&63 (i-group), wave wv = t>>6 owns pairs wv*8..wv*8+7.
    // i = lane + 64*ii (ii<6): av reads 1024B-contiguous per wave; g reads wave-uniform.
    const int lane = t & 63;
    const int wv = t >> 6;

    float acc[8][6];
    #pragma unroll
    for (int pp = 0; pp < 8; ++pp)
        #pragma unroll
        for (int ii = 0; ii < 6; ++ii)
            acc[pp][ii] = 0.f;

    #pragma unroll 1
    for (int c = 0; c < 8; ++c) {
        h2x4 av[6];
        #pragma unroll
        for (int ii = 0; ii < 6; ++ii)
            av[ii] = split4(*reinterpret_cast<const half8v*>(&A2c[(size_t)(c * NN + lane + 64 * ii) * 8]));
        #pragma unroll
        for (int pp = 0; pp < 8; ++pp) {
            const h2x4 g = split4(*reinterpret_cast<const half8v*>(&Gh[(wv * 8 + pp) * 64 + c * 8]));
            #pragma unroll
            for (int ii = 0; ii < 6; ++ii) {
                float s = acc[pp][ii];
                s = __builtin_amdgcn_fdot2(g.v[0], av[ii].v[0], s, false);
                s = __builtin_amdgcn_fdot2(g.v[1], av[ii].v[1], s, false);
                s = __builtin_amdgcn_fdot2(g.v[2], av[ii].v[2], s, false);
                s = __builtin_amdgcn_fdot2(g.v[3], av[ii].v[3], s, false);
                acc[pp][ii] = s;
            }
        }
    }

    // ---- Store: per (pp,ii) the wave's 64 lanes write 256B contiguous.
    float* obase = out + (size_t)(b0 + wv * 8) * NN + lane;
    #pragma unroll
    for (int pp = 0; pp < 8; ++pp) {
        #pragma unroll
        for (int ii = 0; ii < 6; ++ii)
            obase[(size_t)pp * NN + ii * 64] = acc[pp][ii];
    }
}

extern "C" void kernel_launch(void* const* d_in, const int* in_sizes, int n_in,
                              void* d_out, int out_size, void* d_ws, size_t ws_size,
                              hipStream_t stream) {
    const float* A  = (const float*)d_in[0];
    const float* Bf = (const float*)d_in[1];
    const float* C  = (const float*)d_in[2];
    const int*   x  = (const int*)d_in[3];
    float* out = (float*)d_out;
    const int B = in_sizes[3] / 2;           // 524288
    dtn_dot2b<<<B / BB, 512, 0, stream>>>(A, Bf, C, x, out);
}